// Round 1
// baseline (1008.762 us; speedup 1.0000x reference)
//
#include <hip/hip_runtime.h>

#define N_NODES 50000
#define N_EDGES 800000
#define IN_F    128
#define OUT_F   32
#define HEADS   4
#define EDGE_DIM 8
#define LRELU_ALPHA 0.2f

// ---------------------------------------------------------------------------
// K1: xt[n,h,o] = sum_i x[n,i] * W[h,i,o];  alpha_src[n,h] = xt[n,h,:].a_s[h]
//     alpha_dst[n,h] = xt[n,h,:].a_d[h]
// Block: 128 threads = one (h,o) each; NB nodes per block.
// x-row loads are wave-uniform -> scalar loads; W column read from L2.
// ---------------------------------------------------------------------------
template <int NB>
__global__ __launch_bounds__(128) void k_transform(
    const float* __restrict__ x, const float* __restrict__ W,
    const float* __restrict__ a, float* __restrict__ xt,
    float* __restrict__ alpha_src, float* __restrict__ alpha_dst) {
  const int t = threadIdx.x;            // 0..127
  const int h = t >> 5;
  const int o = t & 31;
  const int n0 = blockIdx.x * NB;

  float acc[NB];
#pragma unroll
  for (int nd = 0; nd < NB; ++nd) acc[nd] = 0.f;

  const float* __restrict__ Wc = W + h * (IN_F * OUT_F) + o;  // stride OUT_F over i
  for (int i = 0; i < IN_F; ++i) {
    const float wv = Wc[i * OUT_F];
#pragma unroll
    for (int nd = 0; nd < NB; ++nd) {
      acc[nd] = fmaf(x[(n0 + nd) * IN_F + i], wv, acc[nd]);
    }
  }

  const float as = a[h * 72 + o];
  const float ad = a[h * 72 + 32 + o];
#pragma unroll
  for (int nd = 0; nd < NB; ++nd) {
    const int n = n0 + nd;
    xt[n * 128 + t] = acc[nd];
    float s = acc[nd] * as;
    float d = acc[nd] * ad;
#pragma unroll
    for (int off = 16; off; off >>= 1) {
      s += __shfl_xor(s, off, 64);
      d += __shfl_xor(d, off, 64);
    }
    if (o == 0) {
      alpha_src[n * 4 + h] = s;
      alpha_dst[n * 4 + h] = d;
    }
  }
}

// monotonic float -> uint mapping (order-preserving), for atomicMax
__device__ __forceinline__ unsigned f2key(float f) {
  unsigned b = __float_as_uint(f);
  return (b & 0x80000000u) ? ~b : (b | 0x80000000u);
}
__device__ __forceinline__ float key2f(unsigned k) {
  return (k & 0x80000000u) ? __uint_as_float(k ^ 0x80000000u)
                           : __uint_as_float(~k);
}

__device__ __forceinline__ float edge_score(int e, int src, int dst, int h,
                                            const float* __restrict__ ea,
                                            const float* __restrict__ a,
                                            const float* __restrict__ alpha_src,
                                            const float* __restrict__ alpha_dst) {
  float s = alpha_src[src * 4 + h] + alpha_dst[dst * 4 + h];
#pragma unroll
  for (int k = 0; k < EDGE_DIM; ++k) {
    s = fmaf(ea[e * EDGE_DIM + k], a[h * 72 + 64 + k], s);
  }
  return s > 0.f ? s : LRELU_ALPHA * s;
}

// ---------------------------------------------------------------------------
// K2: per-edge logits, LeakyReLU, atomicMax into per-(dst,h) key
// ---------------------------------------------------------------------------
__global__ __launch_bounds__(256) void k_edge_max(
    const int* __restrict__ ei, const float* __restrict__ ea,
    const float* __restrict__ a, const float* __restrict__ alpha_src,
    const float* __restrict__ alpha_dst, unsigned* __restrict__ max_key) {
  const int e = blockIdx.x * blockDim.x + threadIdx.x;
  if (e >= N_EDGES) return;
  const int src = ei[e];
  const int dst = ei[N_EDGES + e];
#pragma unroll
  for (int h = 0; h < HEADS; ++h) {
    const float s = edge_score(e, src, dst, h, ea, a, alpha_src, alpha_dst);
    atomicMax(&max_key[dst * 4 + h], f2key(s));
  }
}

// ---------------------------------------------------------------------------
// K3: one wave per edge. w = exp(score - max[dst]); atomicAdd sum_exp and
//     numerator out[dst, :] += w * xt[src, :]
// lane handles elements (2*lane, 2*lane+1) of the 128-wide feature vector;
// its head = lane>>4.
// ---------------------------------------------------------------------------
__global__ __launch_bounds__(256) void k_edge_acc(
    const int* __restrict__ ei, const float* __restrict__ ea,
    const float* __restrict__ a, const float* __restrict__ alpha_src,
    const float* __restrict__ alpha_dst, const unsigned* __restrict__ max_key,
    const float* __restrict__ xt, float* __restrict__ sum_exp,
    float* __restrict__ out) {
  const int lane = threadIdx.x & 63;
  const int e = (int)((blockIdx.x * (unsigned)blockDim.x + threadIdx.x) >> 6);
  if (e >= N_EDGES) return;
  const int src = ei[e];
  const int dst = ei[N_EDGES + e];
  const int h = lane >> 4;  // head for this lane's output elements

  const float s = edge_score(e, src, dst, h, ea, a, alpha_src, alpha_dst);
  const float mx = key2f(max_key[dst * 4 + h]);
  const float w = __expf(s - mx);

  if ((lane & 15) == 0) atomicAdd(&sum_exp[dst * 4 + h], w);

  const float2 xv = *reinterpret_cast<const float2*>(&xt[src * 128 + lane * 2]);
  atomicAdd(&out[dst * 128 + lane * 2 + 0], w * xv.x);
  atomicAdd(&out[dst * 128 + lane * 2 + 1], w * xv.y);
}

// ---------------------------------------------------------------------------
// K4: out /= (sum_exp + 1e-10)
// ---------------------------------------------------------------------------
__global__ __launch_bounds__(256) void k_div(float* __restrict__ out,
                                             const float* __restrict__ sum_exp) {
  const int idx = blockIdx.x * blockDim.x + threadIdx.x;
  if (idx >= N_NODES * 128) return;
  const int n = idx >> 7;
  const int h = (idx >> 5) & 3;
  out[idx] = out[idx] / (sum_exp[n * 4 + h] + 1e-10f);
}

extern "C" void kernel_launch(void* const* d_in, const int* in_sizes, int n_in,
                              void* d_out, int out_size, void* d_ws,
                              size_t ws_size, hipStream_t stream) {
  const float* x = (const float*)d_in[0];
  const int* ei = (const int*)d_in[1];
  const float* ea = (const float*)d_in[2];
  const float* W = (const float*)d_in[3];
  const float* a = (const float*)d_in[4];
  float* out = (float*)d_out;

  float* ws = (float*)d_ws;
  float* xt = ws;                                   // 50000*128
  float* alpha_src = xt + (size_t)N_NODES * 128;    // 50000*4
  float* alpha_dst = alpha_src + (size_t)N_NODES * 4;
  unsigned* max_key = (unsigned*)(alpha_dst + (size_t)N_NODES * 4);
  float* sum_exp = (float*)(max_key + (size_t)N_NODES * 4);

  // max_key and sum_exp are contiguous: one memset (key 0 == below all reals)
  hipMemsetAsync(max_key, 0, (size_t)N_NODES * 4 * sizeof(unsigned) * 2, stream);
  hipMemsetAsync(out, 0, (size_t)N_NODES * 128 * sizeof(float), stream);

  k_transform<16><<<N_NODES / 16, 128, 0, stream>>>(x, W, a, xt, alpha_src,
                                                    alpha_dst);
  k_edge_max<<<(N_EDGES + 255) / 256, 256, 0, stream>>>(ei, ea, a, alpha_src,
                                                        alpha_dst, max_key);
  k_edge_acc<<<N_EDGES / 4, 256, 0, stream>>>(ei, ea, a, alpha_src, alpha_dst,
                                              max_key, xt, sum_exp, out);
  k_div<<<(N_NODES * 128 + 255) / 256, 256, 0, stream>>>(out, sum_exp);
}

// Round 2
// 371.327 us; speedup vs baseline: 2.7166x; 2.7166x over previous
//
#include <hip/hip_runtime.h>

#define N_NODES 50000
#define N_EDGES 800000
#define IN_F    128
#define OUT_F   32
#define HEADS   4
#define EDGE_DIM 8
#define LRELU_ALPHA 0.2f

#define SCAN_BLK 1024
#define N_SCAN_BLKS ((N_NODES + SCAN_BLK - 1) / SCAN_BLK)  // 49

// ---------------------------------------------------------------------------
// K1: xt[n,h,o] = sum_i x[n,i] * W[h,i,o];  alpha_src[n,h] = xt[n,h,:].a_s[h]
//     alpha_dst[n,h] = xt[n,h,:].a_d[h]   (unchanged from prev round)
// ---------------------------------------------------------------------------
template <int NB>
__global__ __launch_bounds__(128) void k_transform(
    const float* __restrict__ x, const float* __restrict__ W,
    const float* __restrict__ a, float* __restrict__ xt,
    float* __restrict__ alpha_src, float* __restrict__ alpha_dst) {
  const int t = threadIdx.x;            // 0..127
  const int h = t >> 5;
  const int o = t & 31;
  const int n0 = blockIdx.x * NB;

  float acc[NB];
#pragma unroll
  for (int nd = 0; nd < NB; ++nd) acc[nd] = 0.f;

  const float* __restrict__ Wc = W + h * (IN_F * OUT_F) + o;
  for (int i = 0; i < IN_F; ++i) {
    const float wv = Wc[i * OUT_F];
#pragma unroll
    for (int nd = 0; nd < NB; ++nd) {
      acc[nd] = fmaf(x[(n0 + nd) * IN_F + i], wv, acc[nd]);
    }
  }

  const float as = a[h * 72 + o];
  const float ad = a[h * 72 + 32 + o];
#pragma unroll
  for (int nd = 0; nd < NB; ++nd) {
    const int n = n0 + nd;
    xt[n * 128 + t] = acc[nd];
    float s = acc[nd] * as;
    float d = acc[nd] * ad;
#pragma unroll
    for (int off = 16; off; off >>= 1) {
      s += __shfl_xor(s, off, 64);
      d += __shfl_xor(d, off, 64);
    }
    if (o == 0) {
      alpha_src[n * 4 + h] = s;
      alpha_dst[n * 4 + h] = d;
    }
  }
}

// ---------------------------------------------------------------------------
// K2: histogram of dst
// ---------------------------------------------------------------------------
__global__ __launch_bounds__(256) void k_hist(const int* __restrict__ ei,
                                              unsigned* __restrict__ count) {
  const int e = blockIdx.x * blockDim.x + threadIdx.x;
  if (e >= N_EDGES) return;
  atomicAdd(&count[ei[N_EDGES + e]], 1u);
}

// ---------------------------------------------------------------------------
// K3a/b/c: hierarchical exclusive scan of count[] -> row_start[]
// ---------------------------------------------------------------------------
__global__ __launch_bounds__(SCAN_BLK) void k_scan_a(
    const unsigned* __restrict__ cnt, unsigned* __restrict__ rs,
    unsigned* __restrict__ bsum) {
  __shared__ unsigned wpre[16];
  const int t = threadIdx.x;
  const int i = blockIdx.x * SCAN_BLK + t;
  const int lane = t & 63;
  const int wid = t >> 6;
  unsigned v = (i < N_NODES) ? cnt[i] : 0u;
  unsigned incl = v;
#pragma unroll
  for (int off = 1; off < 64; off <<= 1) {
    unsigned n = __shfl_up(incl, off, 64);
    if (lane >= off) incl += n;
  }
  if (lane == 63) wpre[wid] = incl;
  __syncthreads();
  if (t < 16) {
    unsigned wv = wpre[t];
    unsigned wincl = wv;
#pragma unroll
    for (int off = 1; off < 16; off <<= 1) {
      unsigned n = __shfl_up(wincl, off, 64);
      if (t >= off) wincl += n;
    }
    wpre[t] = wincl - wv;  // exclusive wave prefix
    if (t == 15) bsum[blockIdx.x] = wincl;  // block total
  }
  __syncthreads();
  if (i < N_NODES) rs[i] = incl - v + wpre[wid];
}

__global__ __launch_bounds__(64) void k_scan_b(unsigned* __restrict__ bsum,
                                               unsigned* __restrict__ boff) {
  const int t = threadIdx.x;
  unsigned v = (t < N_SCAN_BLKS) ? bsum[t] : 0u;
  unsigned incl = v;
#pragma unroll
  for (int off = 1; off < 64; off <<= 1) {
    unsigned n = __shfl_up(incl, off, 64);
    if (t >= off) incl += n;
  }
  if (t < N_SCAN_BLKS) boff[t] = incl - v;
}

__global__ __launch_bounds__(SCAN_BLK) void k_scan_c(
    unsigned* __restrict__ rs, const unsigned* __restrict__ boff) {
  const int i = blockIdx.x * SCAN_BLK + threadIdx.x;
  if (i < N_NODES) rs[i] += boff[i >> 10];
  if (i == 0) rs[N_NODES] = N_EDGES;
}

// ---------------------------------------------------------------------------
// K4: scatter edges into CSR slots; precompute the 4 head scores per edge
// ---------------------------------------------------------------------------
__global__ __launch_bounds__(256) void k_scatter(
    const int* __restrict__ ei, const float* __restrict__ ea,
    const float* __restrict__ a, const float* __restrict__ alpha_src,
    const float* __restrict__ alpha_dst, const unsigned* __restrict__ rs,
    unsigned* __restrict__ fill, int* __restrict__ csr_src,
    float4* __restrict__ escore) {
  const int e = blockIdx.x * blockDim.x + threadIdx.x;
  if (e >= N_EDGES) return;
  const int src = ei[e];
  const int dst = ei[N_EDGES + e];
  const unsigned pos = atomicAdd(&fill[dst], 1u);
  const unsigned idx = rs[dst] + pos;
  csr_src[idx] = src;

  const float4 ev0 = *reinterpret_cast<const float4*>(&ea[e * EDGE_DIM]);
  const float4 ev1 = *reinterpret_cast<const float4*>(&ea[e * EDGE_DIM + 4]);
  float4 sc;
  float* scp = reinterpret_cast<float*>(&sc);
#pragma unroll
  for (int h = 0; h < HEADS; ++h) {
    float s = alpha_src[src * 4 + h] + alpha_dst[dst * 4 + h];
    const float* ae = &a[h * 72 + 64];
    s = fmaf(ev0.x, ae[0], s);
    s = fmaf(ev0.y, ae[1], s);
    s = fmaf(ev0.z, ae[2], s);
    s = fmaf(ev0.w, ae[3], s);
    s = fmaf(ev1.x, ae[4], s);
    s = fmaf(ev1.y, ae[5], s);
    s = fmaf(ev1.z, ae[6], s);
    s = fmaf(ev1.w, ae[7], s);
    scp[h] = s > 0.f ? s : LRELU_ALPHA * s;  // h compile-time (unrolled)
  }
  escore[idx] = sc;
}

// ---------------------------------------------------------------------------
// K5: one wave per dst node; online softmax + register accumulation.
// lane l: features 2l, 2l+1 of the 128-wide vector; head = l>>4.
// ---------------------------------------------------------------------------
__global__ __launch_bounds__(256) void k_agg(
    const unsigned* __restrict__ rs, const int* __restrict__ csr_src,
    const float4* __restrict__ escore, const float* __restrict__ xt,
    float* __restrict__ out) {
  const int lane = threadIdx.x & 63;
  const int dst = (int)((blockIdx.x * (unsigned)blockDim.x + threadIdx.x) >> 6);
  if (dst >= N_NODES) return;
  const int h = lane >> 4;

  const unsigned j0 = rs[dst];
  const unsigned j1 = rs[dst + 1];

  float m = -INFINITY;
  float lsum = 0.f, a0 = 0.f, a1 = 0.f;
  for (unsigned j = j0; j < j1; ++j) {
    const float4 s4 = escore[j];
    const int src = csr_src[j];
    const float s = (h & 2) ? ((h & 1) ? s4.w : s4.z)
                            : ((h & 1) ? s4.y : s4.x);
    const float mn = fmaxf(m, s);
    const float scale = __expf(m - mn);   // exp(-inf)=0 on first iter
    const float w = __expf(s - mn);
    const float2 xv =
        *reinterpret_cast<const float2*>(&xt[(size_t)src * 128 + lane * 2]);
    lsum = lsum * scale + w;
    a0 = a0 * scale + w * xv.x;
    a1 = a1 * scale + w * xv.y;
    m = mn;
  }
  const float inv = 1.0f / (lsum + 1e-10f);
  out[(size_t)dst * 128 + lane * 2 + 0] = a0 * inv;
  out[(size_t)dst * 128 + lane * 2 + 1] = a1 * inv;
}

extern "C" void kernel_launch(void* const* d_in, const int* in_sizes, int n_in,
                              void* d_out, int out_size, void* d_ws,
                              size_t ws_size, hipStream_t stream) {
  const float* x = (const float*)d_in[0];
  const int* ei = (const int*)d_in[1];
  const float* ea = (const float*)d_in[2];
  const float* W = (const float*)d_in[3];
  const float* a = (const float*)d_in[4];
  float* out = (float*)d_out;

  // workspace layout
  char* p = (char*)d_ws;
  float* xt = (float*)p;            p += (size_t)N_NODES * 128 * 4;   // 25.6 MB
  float4* escore = (float4*)p;      p += (size_t)N_EDGES * 16;        // 12.8 MB
  float* alpha_src = (float*)p;     p += (size_t)N_NODES * 4 * 4;     // 0.8 MB
  float* alpha_dst = (float*)p;     p += (size_t)N_NODES * 4 * 4;     // 0.8 MB
  int* csr_src = (int*)p;           p += (size_t)N_EDGES * 4;         // 3.2 MB
  unsigned* count = (unsigned*)p;   p += (size_t)N_NODES * 4;         // 0.2 MB
  unsigned* fill = (unsigned*)p;    p += (size_t)N_NODES * 4;         // 0.2 MB
  unsigned* rs = (unsigned*)p;      p += (size_t)(N_NODES + 1) * 4;
  unsigned* bsum = (unsigned*)p;    p += 64 * 4;
  unsigned* boff = (unsigned*)p;    p += 64 * 4;

  // zero count+fill (contiguous)
  hipMemsetAsync(count, 0, (size_t)N_NODES * 4 * 2, stream);

  k_transform<16><<<N_NODES / 16, 128, 0, stream>>>(x, W, a, xt, alpha_src,
                                                    alpha_dst);
  k_hist<<<(N_EDGES + 255) / 256, 256, 0, stream>>>(ei, count);
  k_scan_a<<<N_SCAN_BLKS, SCAN_BLK, 0, stream>>>(count, rs, bsum);
  k_scan_b<<<1, 64, 0, stream>>>(bsum, boff);
  k_scan_c<<<N_SCAN_BLKS, SCAN_BLK, 0, stream>>>(rs, boff);
  k_scatter<<<(N_EDGES + 255) / 256, 256, 0, stream>>>(
      ei, ea, a, alpha_src, alpha_dst, rs, fill, csr_src, escore);
  k_agg<<<(N_NODES * 64 + 255) / 256, 256, 0, stream>>>(rs, csr_src, escore,
                                                        xt, out);
}

// Round 3
// 248.705 us; speedup vs baseline: 4.0561x; 1.4930x over previous
//
#include <hip/hip_runtime.h>

#define N_NODES 50000
#define N_EDGES 800000
#define IN_F    128
#define OUT_F   32
#define HEADS   4
#define EDGE_DIM 8
#define LRELU_ALPHA 0.2f

#define SCAN_BLK 1024
#define N_SCAN_BLKS ((N_NODES + SCAN_BLK - 1) / SCAN_BLK)  // 49

// ---------------------------------------------------------------------------
// K1: LDS-tiled fp32 GEMM. xt[n,ho] = sum_i x[n,i] * W[h,i,o], 64 nodes/block.
// Thread t: 4 consecutive ho columns (ho0 = (t&31)*4), 8 nodes (group t>>5).
// Per k-step: 1 float4 W load + 8 LDS broadcasts + 32 FMA.
// Epilogue: fused alpha_src/alpha_dst reduction (4-dot + shfl over o-group).
// ---------------------------------------------------------------------------
__global__ __launch_bounds__(256) void k_transform(
    const float* __restrict__ x, const float* __restrict__ W,
    const float* __restrict__ a, float* __restrict__ xt,
    float* __restrict__ alpha_src, float* __restrict__ alpha_dst) {
  __shared__ float sx[64][128];
  const int t = threadIdx.x;
  const int n0 = blockIdx.x * 64;

  // stage x tile (coalesced float4; ds_write_b128 conflict-free)
#pragma unroll
  for (int r = 0; r < 8; ++r) {
    const int f = r * 256 + t;   // float4 index within 64x128 tile
    const int node = f >> 5;
    const int i4 = (f & 31) * 4;
    const int n = n0 + node;
    float4 v = make_float4(0.f, 0.f, 0.f, 0.f);
    if (n < N_NODES) v = *reinterpret_cast<const float4*>(&x[(size_t)n * 128 + i4]);
    *reinterpret_cast<float4*>(&sx[node][i4]) = v;
  }
  __syncthreads();

  const int lane31 = t & 31;
  const int ng = t >> 5;          // node group 0..7
  const int ho0 = lane31 * 4;     // 4 consecutive output columns
  const int h = ho0 >> 5;
  const int o0 = ho0 & 31;

  float acc[8][4];
#pragma unroll
  for (int nd = 0; nd < 8; ++nd)
#pragma unroll
    for (int j = 0; j < 4; ++j) acc[nd][j] = 0.f;

  const float* __restrict__ wp = W + h * (IN_F * OUT_F) + o0;
#pragma unroll 4
  for (int i = 0; i < IN_F; ++i) {
    const float4 wv = *reinterpret_cast<const float4*>(&wp[i * OUT_F]);
#pragma unroll
    for (int nd = 0; nd < 8; ++nd) {
      const float xv = sx[ng * 8 + nd][i];
      acc[nd][0] = fmaf(xv, wv.x, acc[nd][0]);
      acc[nd][1] = fmaf(xv, wv.y, acc[nd][1]);
      acc[nd][2] = fmaf(xv, wv.z, acc[nd][2]);
      acc[nd][3] = fmaf(xv, wv.w, acc[nd][3]);
    }
  }

  // store xt (half-wave covers one 512B row -> coalesced)
#pragma unroll
  for (int nd = 0; nd < 8; ++nd) {
    const int n = n0 + ng * 8 + nd;
    if (n < N_NODES) {
      *reinterpret_cast<float4*>(&xt[(size_t)n * 128 + ho0]) =
          make_float4(acc[nd][0], acc[nd][1], acc[nd][2], acc[nd][3]);
    }
  }

  // fused alpha reduction: alpha_*[n,h] = sum_o xt[n,h,o] * a_*[h,o]
  const float4 as4 = *reinterpret_cast<const float4*>(&a[h * 72 + o0]);
  const float4 ad4 = *reinterpret_cast<const float4*>(&a[h * 72 + 32 + o0]);
#pragma unroll
  for (int nd = 0; nd < 8; ++nd) {
    float s = acc[nd][0] * as4.x + acc[nd][1] * as4.y + acc[nd][2] * as4.z +
              acc[nd][3] * as4.w;
    float d = acc[nd][0] * ad4.x + acc[nd][1] * ad4.y + acc[nd][2] * ad4.z +
              acc[nd][3] * ad4.w;
    s += __shfl_xor(s, 1, 64); d += __shfl_xor(d, 1, 64);
    s += __shfl_xor(s, 2, 64); d += __shfl_xor(d, 2, 64);
    s += __shfl_xor(s, 4, 64); d += __shfl_xor(d, 4, 64);
    if ((t & 7) == 0) {
      const int n = n0 + ng * 8 + nd;
      if (n < N_NODES) {
        alpha_src[n * 4 + h] = s;
        alpha_dst[n * 4 + h] = d;
      }
    }
  }
}

// ---------------------------------------------------------------------------
// K2: histogram of dst
// ---------------------------------------------------------------------------
__global__ __launch_bounds__(256) void k_hist(const int* __restrict__ ei,
                                              unsigned* __restrict__ count) {
  const int e = blockIdx.x * blockDim.x + threadIdx.x;
  if (e >= N_EDGES) return;
  atomicAdd(&count[ei[N_EDGES + e]], 1u);
}

// ---------------------------------------------------------------------------
// K3a/b/c: hierarchical exclusive scan of count[] -> row_start[]
// ---------------------------------------------------------------------------
__global__ __launch_bounds__(SCAN_BLK) void k_scan_a(
    const unsigned* __restrict__ cnt, unsigned* __restrict__ rs,
    unsigned* __restrict__ bsum) {
  __shared__ unsigned wpre[16];
  const int t = threadIdx.x;
  const int i = blockIdx.x * SCAN_BLK + t;
  const int lane = t & 63;
  const int wid = t >> 6;
  unsigned v = (i < N_NODES) ? cnt[i] : 0u;
  unsigned incl = v;
#pragma unroll
  for (int off = 1; off < 64; off <<= 1) {
    unsigned n = __shfl_up(incl, off, 64);
    if (lane >= off) incl += n;
  }
  if (lane == 63) wpre[wid] = incl;
  __syncthreads();
  if (t < 16) {
    unsigned wv = wpre[t];
    unsigned wincl = wv;
#pragma unroll
    for (int off = 1; off < 16; off <<= 1) {
      unsigned n = __shfl_up(wincl, off, 64);
      if (t >= off) wincl += n;
    }
    wpre[t] = wincl - wv;  // exclusive wave prefix
    if (t == 15) bsum[blockIdx.x] = wincl;  // block total
  }
  __syncthreads();
  if (i < N_NODES) rs[i] = incl - v + wpre[wid];
}

__global__ __launch_bounds__(64) void k_scan_b(unsigned* __restrict__ bsum,
                                               unsigned* __restrict__ boff) {
  const int t = threadIdx.x;
  unsigned v = (t < N_SCAN_BLKS) ? bsum[t] : 0u;
  unsigned incl = v;
#pragma unroll
  for (int off = 1; off < 64; off <<= 1) {
    unsigned n = __shfl_up(incl, off, 64);
    if (t >= off) incl += n;
  }
  if (t < N_SCAN_BLKS) boff[t] = incl - v;
}

__global__ __launch_bounds__(SCAN_BLK) void k_scan_c(
    unsigned* __restrict__ rs, const unsigned* __restrict__ boff) {
  const int i = blockIdx.x * SCAN_BLK + threadIdx.x;
  if (i < N_NODES) rs[i] += boff[i >> 10];
  if (i == 0) rs[N_NODES] = N_EDGES;
}

// ---------------------------------------------------------------------------
// K4: scatter edges into CSR slots; precompute the 4 head scores per edge
// ---------------------------------------------------------------------------
__global__ __launch_bounds__(256) void k_scatter(
    const int* __restrict__ ei, const float* __restrict__ ea,
    const float* __restrict__ a, const float* __restrict__ alpha_src,
    const float* __restrict__ alpha_dst, const unsigned* __restrict__ rs,
    unsigned* __restrict__ fill, int* __restrict__ csr_src,
    float4* __restrict__ escore) {
  const int e = blockIdx.x * blockDim.x + threadIdx.x;
  if (e >= N_EDGES) return;
  const int src = ei[e];
  const int dst = ei[N_EDGES + e];
  const unsigned pos = atomicAdd(&fill[dst], 1u);
  const unsigned idx = rs[dst] + pos;
  csr_src[idx] = src;

  const float4 ev0 = *reinterpret_cast<const float4*>(&ea[e * EDGE_DIM]);
  const float4 ev1 = *reinterpret_cast<const float4*>(&ea[e * EDGE_DIM + 4]);
  const float4 als = *reinterpret_cast<const float4*>(&alpha_src[src * 4]);
  const float4 ald = *reinterpret_cast<const float4*>(&alpha_dst[dst * 4]);
  const float* alsp = reinterpret_cast<const float*>(&als);
  const float* aldp = reinterpret_cast<const float*>(&ald);
  float4 sc;
  float* scp = reinterpret_cast<float*>(&sc);
#pragma unroll
  for (int h = 0; h < HEADS; ++h) {
    float s = alsp[h] + aldp[h];
    const float* ae = &a[h * 72 + 64];
    s = fmaf(ev0.x, ae[0], s);
    s = fmaf(ev0.y, ae[1], s);
    s = fmaf(ev0.z, ae[2], s);
    s = fmaf(ev0.w, ae[3], s);
    s = fmaf(ev1.x, ae[4], s);
    s = fmaf(ev1.y, ae[5], s);
    s = fmaf(ev1.z, ae[6], s);
    s = fmaf(ev1.w, ae[7], s);
    scp[h] = s > 0.f ? s : LRELU_ALPHA * s;
  }
  escore[idx] = sc;
}

// ---------------------------------------------------------------------------
// K5: one wave per dst node; online softmax + register accumulation.
// lane l: features 2l, 2l+1 of the 128-wide vector; head = l>>4.
// ---------------------------------------------------------------------------
__global__ __launch_bounds__(256) void k_agg(
    const unsigned* __restrict__ rs, const int* __restrict__ csr_src,
    const float4* __restrict__ escore, const float* __restrict__ xt,
    float* __restrict__ out) {
  const int lane = threadIdx.x & 63;
  const int dst = (int)((blockIdx.x * (unsigned)blockDim.x + threadIdx.x) >> 6);
  if (dst >= N_NODES) return;
  const int h = lane >> 4;

  const unsigned j0 = rs[dst];
  const unsigned j1 = rs[dst + 1];

  float m = -INFINITY;
  float lsum = 0.f, a0 = 0.f, a1 = 0.f;
  for (unsigned j = j0; j < j1; ++j) {
    const float4 s4 = escore[j];
    const int src = csr_src[j];
    const float s = (h & 2) ? ((h & 1) ? s4.w : s4.z)
                            : ((h & 1) ? s4.y : s4.x);
    const float mn = fmaxf(m, s);
    const float scale = __expf(m - mn);   // exp(-inf)=0 on first iter
    const float w = __expf(s - mn);
    const float2 xv =
        *reinterpret_cast<const float2*>(&xt[(size_t)src * 128 + lane * 2]);
    lsum = lsum * scale + w;
    a0 = a0 * scale + w * xv.x;
    a1 = a1 * scale + w * xv.y;
    m = mn;
  }
  const float inv = 1.0f / (lsum + 1e-10f);
  out[(size_t)dst * 128 + lane * 2 + 0] = a0 * inv;
  out[(size_t)dst * 128 + lane * 2 + 1] = a1 * inv;
}

extern "C" void kernel_launch(void* const* d_in, const int* in_sizes, int n_in,
                              void* d_out, int out_size, void* d_ws,
                              size_t ws_size, hipStream_t stream) {
  const float* x = (const float*)d_in[0];
  const int* ei = (const int*)d_in[1];
  const float* ea = (const float*)d_in[2];
  const float* W = (const float*)d_in[3];
  const float* a = (const float*)d_in[4];
  float* out = (float*)d_out;

  // workspace layout
  char* p = (char*)d_ws;
  float* xt = (float*)p;            p += (size_t)N_NODES * 128 * 4;   // 25.6 MB
  float4* escore = (float4*)p;      p += (size_t)N_EDGES * 16;        // 12.8 MB
  float* alpha_src = (float*)p;     p += (size_t)N_NODES * 4 * 4;     // 0.8 MB
  float* alpha_dst = (float*)p;     p += (size_t)N_NODES * 4 * 4;     // 0.8 MB
  int* csr_src = (int*)p;           p += (size_t)N_EDGES * 4;         // 3.2 MB
  unsigned* count = (unsigned*)p;   p += (size_t)N_NODES * 4;         // 0.2 MB
  unsigned* fill = (unsigned*)p;    p += (size_t)N_NODES * 4;         // 0.2 MB
  unsigned* rs = (unsigned*)p;      p += (size_t)(N_NODES + 1) * 4;
  unsigned* bsum = (unsigned*)p;    p += 64 * 4;
  unsigned* boff = (unsigned*)p;    p += 64 * 4;

  // zero count+fill (contiguous)
  hipMemsetAsync(count, 0, (size_t)N_NODES * 4 * 2, stream);

  k_transform<<<(N_NODES + 63) / 64, 256, 0, stream>>>(x, W, a, xt, alpha_src,
                                                       alpha_dst);
  k_hist<<<(N_EDGES + 255) / 256, 256, 0, stream>>>(ei, count);
  k_scan_a<<<N_SCAN_BLKS, SCAN_BLK, 0, stream>>>(count, rs, bsum);
  k_scan_b<<<1, 64, 0, stream>>>(bsum, boff);
  k_scan_c<<<N_SCAN_BLKS, SCAN_BLK, 0, stream>>>(rs, boff);
  k_scatter<<<(N_EDGES + 255) / 256, 256, 0, stream>>>(
      ei, ea, a, alpha_src, alpha_dst, rs, fill, csr_src, escore);
  k_agg<<<(N_NODES * 64 + 255) / 256, 256, 0, stream>>>(rs, csr_src, escore,
                                                        xt, out);
}

// Round 4
// 190.333 us; speedup vs baseline: 5.3000x; 1.3067x over previous
//
#include <hip/hip_runtime.h>

#define N_NODES 50000
#define N_EDGES 800000
#define IN_F    128
#define OUT_F   32
#define HEADS   4
#define EDGE_DIM 8
#define LRELU_ALPHA 0.2f

#define SCAN_BLK 1024
#define N_SCAN_BLKS ((N_NODES + SCAN_BLK - 1) / SCAN_BLK)  // 49

// round-to-nearest-even f32 -> bf16 (as ushort in low bits)
__device__ __forceinline__ unsigned f2bf(float f) {
  unsigned u = __float_as_uint(f);
  return (u + 0x7fffu + ((u >> 16) & 1u)) >> 16;
}

// ---------------------------------------------------------------------------
// K1: LDS-tiled fp32 GEMM. xt[n,ho] = sum_i x[n,i] * W[h,i,o], 64 nodes/block.
// Output xt stored as packed bf16 pairs: xtb[n*64 + k] = features (2k, 2k+1).
// Epilogue: fused alpha_src/alpha_dst reduction (fp32, unaffected by bf16).
// ---------------------------------------------------------------------------
__global__ __launch_bounds__(256) void k_transform(
    const float* __restrict__ x, const float* __restrict__ W,
    const float* __restrict__ a, unsigned* __restrict__ xtb,
    float* __restrict__ alpha_src, float* __restrict__ alpha_dst) {
  __shared__ float sx[64][128];
  const int t = threadIdx.x;
  const int n0 = blockIdx.x * 64;

  // stage x tile (coalesced float4)
#pragma unroll
  for (int r = 0; r < 8; ++r) {
    const int f = r * 256 + t;   // float4 index within 64x128 tile
    const int node = f >> 5;
    const int i4 = (f & 31) * 4;
    const int n = n0 + node;
    float4 v = make_float4(0.f, 0.f, 0.f, 0.f);
    if (n < N_NODES) v = *reinterpret_cast<const float4*>(&x[(size_t)n * 128 + i4]);
    *reinterpret_cast<float4*>(&sx[node][i4]) = v;
  }
  __syncthreads();

  const int lane31 = t & 31;
  const int ng = t >> 5;          // node group 0..7
  const int ho0 = lane31 * 4;     // 4 consecutive output columns
  const int h = ho0 >> 5;
  const int o0 = ho0 & 31;

  float acc[8][4];
#pragma unroll
  for (int nd = 0; nd < 8; ++nd)
#pragma unroll
    for (int j = 0; j < 4; ++j) acc[nd][j] = 0.f;

  const float* __restrict__ wp = W + h * (IN_F * OUT_F) + o0;
#pragma unroll 4
  for (int i = 0; i < IN_F; ++i) {
    const float4 wv = *reinterpret_cast<const float4*>(&wp[i * OUT_F]);
#pragma unroll
    for (int nd = 0; nd < 8; ++nd) {
      const float xv = sx[ng * 8 + nd][i];
      acc[nd][0] = fmaf(xv, wv.x, acc[nd][0]);
      acc[nd][1] = fmaf(xv, wv.y, acc[nd][1]);
      acc[nd][2] = fmaf(xv, wv.z, acc[nd][2]);
      acc[nd][3] = fmaf(xv, wv.w, acc[nd][3]);
    }
  }

  // store xt as packed bf16 (8 B per thread per node)
#pragma unroll
  for (int nd = 0; nd < 8; ++nd) {
    const int n = n0 + ng * 8 + nd;
    if (n < N_NODES) {
      uint2 pk;
      pk.x = f2bf(acc[nd][0]) | (f2bf(acc[nd][1]) << 16);
      pk.y = f2bf(acc[nd][2]) | (f2bf(acc[nd][3]) << 16);
      *reinterpret_cast<uint2*>(&xtb[(size_t)n * 64 + lane31 * 2]) = pk;
    }
  }

  // fused alpha reduction: alpha_*[n,h] = sum_o xt[n,h,o] * a_*[h,o]
  const float4 as4 = *reinterpret_cast<const float4*>(&a[h * 72 + o0]);
  const float4 ad4 = *reinterpret_cast<const float4*>(&a[h * 72 + 32 + o0]);
#pragma unroll
  for (int nd = 0; nd < 8; ++nd) {
    float s = acc[nd][0] * as4.x + acc[nd][1] * as4.y + acc[nd][2] * as4.z +
              acc[nd][3] * as4.w;
    float d = acc[nd][0] * ad4.x + acc[nd][1] * ad4.y + acc[nd][2] * ad4.z +
              acc[nd][3] * ad4.w;
    s += __shfl_xor(s, 1, 64); d += __shfl_xor(d, 1, 64);
    s += __shfl_xor(s, 2, 64); d += __shfl_xor(d, 2, 64);
    s += __shfl_xor(s, 4, 64); d += __shfl_xor(d, 4, 64);
    if ((t & 7) == 0) {
      const int n = n0 + ng * 8 + nd;
      if (n < N_NODES) {
        alpha_src[n * 4 + h] = s;
        alpha_dst[n * 4 + h] = d;
      }
    }
  }
}

// ---------------------------------------------------------------------------
// K2: histogram of dst
// ---------------------------------------------------------------------------
__global__ __launch_bounds__(256) void k_hist(const int* __restrict__ ei,
                                              unsigned* __restrict__ count) {
  const int e = blockIdx.x * blockDim.x + threadIdx.x;
  if (e >= N_EDGES) return;
  atomicAdd(&count[ei[N_EDGES + e]], 1u);
}

// ---------------------------------------------------------------------------
// K3a/b/c: hierarchical exclusive scan of count[] -> row_start[]
// ---------------------------------------------------------------------------
__global__ __launch_bounds__(SCAN_BLK) void k_scan_a(
    const unsigned* __restrict__ cnt, unsigned* __restrict__ rs,
    unsigned* __restrict__ bsum) {
  __shared__ unsigned wpre[16];
  const int t = threadIdx.x;
  const int i = blockIdx.x * SCAN_BLK + t;
  const int lane = t & 63;
  const int wid = t >> 6;
  unsigned v = (i < N_NODES) ? cnt[i] : 0u;
  unsigned incl = v;
#pragma unroll
  for (int off = 1; off < 64; off <<= 1) {
    unsigned n = __shfl_up(incl, off, 64);
    if (lane >= off) incl += n;
  }
  if (lane == 63) wpre[wid] = incl;
  __syncthreads();
  if (t < 16) {
    unsigned wv = wpre[t];
    unsigned wincl = wv;
#pragma unroll
    for (int off = 1; off < 16; off <<= 1) {
      unsigned n = __shfl_up(wincl, off, 64);
      if (t >= off) wincl += n;
    }
    wpre[t] = wincl - wv;  // exclusive wave prefix
    if (t == 15) bsum[blockIdx.x] = wincl;  // block total
  }
  __syncthreads();
  if (i < N_NODES) rs[i] = incl - v + wpre[wid];
}

__global__ __launch_bounds__(64) void k_scan_b(unsigned* __restrict__ bsum,
                                               unsigned* __restrict__ boff) {
  const int t = threadIdx.x;
  unsigned v = (t < N_SCAN_BLKS) ? bsum[t] : 0u;
  unsigned incl = v;
#pragma unroll
  for (int off = 1; off < 64; off <<= 1) {
    unsigned n = __shfl_up(incl, off, 64);
    if (t >= off) incl += n;
  }
  if (t < N_SCAN_BLKS) boff[t] = incl - v;
}

__global__ __launch_bounds__(SCAN_BLK) void k_scan_c(
    unsigned* __restrict__ rs, const unsigned* __restrict__ boff) {
  const int i = blockIdx.x * SCAN_BLK + threadIdx.x;
  if (i < N_NODES) rs[i] += boff[i >> 10];
  if (i == 0) rs[N_NODES] = N_EDGES;
}

// ---------------------------------------------------------------------------
// K4: scatter edges into CSR slots; precompute the 4 head scores per edge
// ---------------------------------------------------------------------------
__global__ __launch_bounds__(256) void k_scatter(
    const int* __restrict__ ei, const float* __restrict__ ea,
    const float* __restrict__ a, const float* __restrict__ alpha_src,
    const float* __restrict__ alpha_dst, const unsigned* __restrict__ rs,
    unsigned* __restrict__ fill, int* __restrict__ csr_src,
    float4* __restrict__ escore) {
  const int e = blockIdx.x * blockDim.x + threadIdx.x;
  if (e >= N_EDGES) return;
  const int src = ei[e];
  const int dst = ei[N_EDGES + e];
  const unsigned pos = atomicAdd(&fill[dst], 1u);
  const unsigned idx = rs[dst] + pos;
  csr_src[idx] = src;

  const float4 ev0 = *reinterpret_cast<const float4*>(&ea[e * EDGE_DIM]);
  const float4 ev1 = *reinterpret_cast<const float4*>(&ea[e * EDGE_DIM + 4]);
  const float4 als = *reinterpret_cast<const float4*>(&alpha_src[src * 4]);
  const float4 ald = *reinterpret_cast<const float4*>(&alpha_dst[dst * 4]);
  const float* alsp = reinterpret_cast<const float*>(&als);
  const float* aldp = reinterpret_cast<const float*>(&ald);
  float4 sc;
  float* scp = reinterpret_cast<float*>(&sc);
#pragma unroll
  for (int h = 0; h < HEADS; ++h) {
    float s = alsp[h] + aldp[h];
    const float* ae = &a[h * 72 + 64];
    s = fmaf(ev0.x, ae[0], s);
    s = fmaf(ev0.y, ae[1], s);
    s = fmaf(ev0.z, ae[2], s);
    s = fmaf(ev0.w, ae[3], s);
    s = fmaf(ev1.x, ae[4], s);
    s = fmaf(ev1.y, ae[5], s);
    s = fmaf(ev1.z, ae[6], s);
    s = fmaf(ev1.w, ae[7], s);
    scp[h] = s > 0.f ? s : LRELU_ALPHA * s;
  }
  escore[idx] = sc;
}

// ---------------------------------------------------------------------------
// K5: one wave per dst. Lane-parallel softmax over CSR-contiguous scores
// (score of edge j0+(l>>2), head l&3 per lane), then batched gather pass:
// 16 edges/round, w and src broadcast via shfl, 16 independent bf16 gathers.
// lane l accumulates features 2l, 2l+1 (head l>>4).
// ---------------------------------------------------------------------------
__global__ __launch_bounds__(256) void k_agg(
    const unsigned* __restrict__ rs, const int* __restrict__ csr_src,
    const float* __restrict__ escore_f, const unsigned* __restrict__ xtb,
    float* __restrict__ out) {
  const int lane = threadIdx.x & 63;
  const int dst = (int)((blockIdx.x * (unsigned)blockDim.x + threadIdx.x) >> 6);
  if (dst >= N_NODES) return;

  const unsigned j0 = rs[dst];
  const unsigned j1 = rs[dst + 1];
  const int deg = (int)(j1 - j0);

  float a0 = 0.f, a1 = 0.f, lsum = 0.f;

  if (deg > 0) {
    const int rounds = (deg + 15) >> 4;
    const int sub = lane >> 2;   // edge-within-round handled in score space
    const int hA = lane & 3;     // head handled in score space
    const int hB = lane >> 4;    // head of this lane's output features

    // pass 1: per-head max (coalesced 256B score reads)
    float m = -INFINITY;
    for (int r = 0; r < rounds; ++r) {
      const int j = (int)j0 + r * 16 + sub;
      const float s =
          (j < (int)j1) ? escore_f[(size_t)j * 4 + hA] : -INFINITY;
      m = fmaxf(m, s);
    }
    m = fmaxf(m, __shfl_xor(m, 4, 64));
    m = fmaxf(m, __shfl_xor(m, 8, 64));
    m = fmaxf(m, __shfl_xor(m, 16, 64));
    m = fmaxf(m, __shfl_xor(m, 32, 64));

    // pass 2: weights + batched gather-accumulate
    for (int r = 0; r < rounds; ++r) {
      const int base = (int)j0 + r * 16;
      const int j = base + sub;
      const float s =
          (j < (int)j1) ? escore_f[(size_t)j * 4 + hA] : -INFINITY;
      const float w = __expf(s - m);   // padded lanes: exp(-inf)=0
      lsum += w;
      const int jc = base + (lane & 15);
      const int srcv = (jc < (int)j1) ? csr_src[jc] : 0;
      const int nedge = min(16, deg - r * 16);
#pragma unroll 4
      for (int jj = 0; jj < nedge; ++jj) {
        const int src = __shfl(srcv, jj, 64);
        const float wj = __shfl(w, 4 * jj + hB, 64);
        const unsigned u = xtb[(size_t)src * 64 + lane];
        a0 = fmaf(wj, __uint_as_float(u << 16), a0);
        a1 = fmaf(wj, __uint_as_float(u & 0xffff0000u), a1);
      }
    }
    lsum += __shfl_xor(lsum, 4, 64);
    lsum += __shfl_xor(lsum, 8, 64);
    lsum += __shfl_xor(lsum, 16, 64);
    lsum += __shfl_xor(lsum, 32, 64);
    lsum = __shfl(lsum, hB, 64);   // lane hB holds head hB's sum
  }

  const float inv = 1.0f / (lsum + 1e-10f);
  out[(size_t)dst * 128 + lane * 2 + 0] = a0 * inv;
  out[(size_t)dst * 128 + lane * 2 + 1] = a1 * inv;
}

extern "C" void kernel_launch(void* const* d_in, const int* in_sizes, int n_in,
                              void* d_out, int out_size, void* d_ws,
                              size_t ws_size, hipStream_t stream) {
  const float* x = (const float*)d_in[0];
  const int* ei = (const int*)d_in[1];
  const float* ea = (const float*)d_in[2];
  const float* W = (const float*)d_in[3];
  const float* a = (const float*)d_in[4];
  float* out = (float*)d_out;

  // workspace layout
  char* p = (char*)d_ws;
  unsigned* xtb = (unsigned*)p;     p += (size_t)N_NODES * 64 * 4;    // 12.8 MB
  float4* escore = (float4*)p;      p += (size_t)N_EDGES * 16;        // 12.8 MB
  float* alpha_src = (float*)p;     p += (size_t)N_NODES * 4 * 4;     // 0.8 MB
  float* alpha_dst = (float*)p;     p += (size_t)N_NODES * 4 * 4;     // 0.8 MB
  int* csr_src = (int*)p;           p += (size_t)N_EDGES * 4;         // 3.2 MB
  unsigned* count = (unsigned*)p;   p += (size_t)N_NODES * 4;         // 0.2 MB
  unsigned* fill = (unsigned*)p;    p += (size_t)N_NODES * 4;         // 0.2 MB
  unsigned* rs = (unsigned*)p;      p += (size_t)(N_NODES + 1) * 4;
  unsigned* bsum = (unsigned*)p;    p += 64 * 4;
  unsigned* boff = (unsigned*)p;    p += 64 * 4;

  // zero count+fill (contiguous)
  hipMemsetAsync(count, 0, (size_t)N_NODES * 4 * 2, stream);

  k_transform<<<(N_NODES + 63) / 64, 256, 0, stream>>>(x, W, a, xtb, alpha_src,
                                                       alpha_dst);
  k_hist<<<(N_EDGES + 255) / 256, 256, 0, stream>>>(ei, count);
  k_scan_a<<<N_SCAN_BLKS, SCAN_BLK, 0, stream>>>(count, rs, bsum);
  k_scan_b<<<1, 64, 0, stream>>>(bsum, boff);
  k_scan_c<<<N_SCAN_BLKS, SCAN_BLK, 0, stream>>>(rs, boff);
  k_scatter<<<(N_EDGES + 255) / 256, 256, 0, stream>>>(
      ei, ea, a, alpha_src, alpha_dst, rs, fill, csr_src, escore);
  k_agg<<<(N_NODES * 64 + 255) / 256, 256, 0, stream>>>(
      rs, csr_src, (const float*)escore, xtb, out);
}